// Round 14
// baseline (366.151 us; speedup 1.0000x reference)
//
#include <hip/hip_runtime.h>
#include <hip/hip_bf16.h>
#include <math.h>

// DIEN bf16-MFMA v12: v11 fused recurrence, but register cap forced via
// amdgpu_waves_per_eu(2,2) (min=max=2 waves/EU -> exactly 256 VGPR budget).
// v11's __launch_bounds__(512,1) only set a MINIMUM; allocator still targeted
// 4 waves/EU -> 128 regs -> per-step weight remat (FETCH 300MB, 365us).
// ws layout (bytes): unchanged.

#define LK 0.0003f

typedef __attribute__((ext_vector_type(8))) short short8;
typedef __attribute__((ext_vector_type(4))) float f32x4;

__device__ __forceinline__ float sigf(float x) {
    return __builtin_amdgcn_rcpf(1.0f + __expf(-x));
}
__device__ __forceinline__ float tanhfast(float x) {
    return fmaf(2.0f, __builtin_amdgcn_rcpf(1.0f + __expf(-2.0f * x)), -1.0f);
}
__device__ __forceinline__ float lky(float v) { return v >= 0.0f ? v : LK * v; }
__device__ __forceinline__ unsigned short f2bf(float f) {
    __bf16 b = (__bf16)f;
    return *reinterpret_cast<unsigned short*>(&b);
}
__device__ __forceinline__ unsigned pk2(float a, float b) {
    return (unsigned)f2bf(a) | ((unsigned)f2bf(b) << 16);
}
__device__ __forceinline__ int swz(int row, int kbyte, int stride) {
    return row * stride + (kbyte ^ ((row & 7) << 4));
}
__device__ __forceinline__ f32x4 mfma16(short8 a, short8 b, f32x4 c) {
    return __builtin_amdgcn_mfma_f32_16x16x32_bf16(a, b, c, 0, 0, 0);
}
__device__ __forceinline__ void barrier_lds() {
    __builtin_amdgcn_sched_barrier(0);
    asm volatile("s_waitcnt lgkmcnt(0)" ::: "memory");
    __builtin_amdgcn_sched_barrier(0);
    __builtin_amdgcn_s_barrier();
    __builtin_amdgcn_sched_barrier(0);
}

// ---------------- pack & transpose all weights to bf16 [n][k] panels ----------------
__global__ void pack_all(
    const float* __restrict__ gW, const float* __restrict__ gU,
    const float* __restrict__ aWu, const float* __restrict__ aWr, const float* __restrict__ aWc,
    const float* __restrict__ aUu, const float* __restrict__ aUr, const float* __restrict__ aUc,
    const float* __restrict__ tW1, const float* __restrict__ tW2,
    const float* __restrict__ dW1, const float* __restrict__ dW2,
    const float* __restrict__ abu, const float* __restrict__ abr, const float* __restrict__ abc,
    unsigned short* __restrict__ Wg, unsigned short* __restrict__ Ug,
    unsigned short* __restrict__ Wau, unsigned short* __restrict__ Uau,
    unsigned short* __restrict__ WA, unsigned short* __restrict__ WN,
    unsigned short* __restrict__ AW2,
    unsigned short* __restrict__ DW1, unsigned short* __restrict__ DW2,
    float* __restrict__ bp)
{
    int i = blockIdx.x * 256 + threadIdx.x;
    if (i < 49152) {
        int n = i >> 7, k = i & 127;
        Wg[i] = f2bf(gW[k * 384 + n]);
        Ug[i] = f2bf(gU[k * 384 + n]);
    } else if (i < 98304) {
        int j = i - 49152; int n = j >> 7, k = j & 127;
        int g = n >> 7, c = n & 127;
        const float* s = (g == 0) ? aWu : (g == 1) ? aWr : aWc;
        const float* u = (g == 0) ? aUu : (g == 1) ? aUr : aUc;
        Wau[j] = f2bf(s[k * 128 + c]);
        Uau[j] = f2bf(u[k * 128 + c]);
    } else if (i < 131072) {
        int j = i - 98304; int n = j >> 8, k = j & 255;
        float v = (k < 128) ? (tW1[k * 128 + n] - tW1[(128 + k) * 128 + n])
                            : tW1[(384 + (k - 128)) * 128 + n];
        WA[j] = f2bf(v);
    } else if (i < 147456) {
        int j = i - 131072; int n = j >> 7, k = j & 127;
        WN[j] = f2bf(tW1[(128 + k) * 128 + n] + tW1[(256 + k) * 128 + n]);
    } else if (i < 155648) {
        int j = i - 147456; int n = j >> 7, k = j & 127;
        AW2[j] = f2bf(tW2[k * 64 + n]);
    } else if (i < 221184) {
        int j = i - 155648; int n = j >> 8, k = j & 255;
        DW1[j] = f2bf(dW1[k * 256 + n]);
    } else if (i < 253952) {
        int j = i - 221184; int n = j >> 8, k = j & 255;
        DW2[j] = f2bf(dW2[k * 128 + n]);
    } else if (i < 254336) {
        int j = i - 253952;
        bp[j] = (j < 128) ? abu[j] : (j < 256) ? abr[j - 128] : abc[j - 256];
    }
}

// ---------------- nterm = news @ WN + b1 ----------------
__global__ __launch_bounds__(512, 2) void nterm_kernel(
    const float* __restrict__ inputs, const unsigned short* __restrict__ WN,
    const float* __restrict__ b1, float* __restrict__ nterm)
{
    __shared__ __align__(16) unsigned char nb[64 * 256];

    const int tid = threadIdx.x;
    const int wv = tid >> 6, l = tid & 63, l15 = l & 15, lg = l >> 4;
    const size_t b0 = (size_t)blockIdx.x * 64;

    {
        int r = tid >> 3, c = tid & 7;
        const float* src = inputs + ((b0 + r) * 51 + 50) * 128 + c * 16;
        float4 v0 = *(const float4*)(src);
        float4 v1 = *(const float4*)(src + 4);
        float4 v2 = *(const float4*)(src + 8);
        float4 v3 = *(const float4*)(src + 12);
        *(uint4*)(nb + swz(r, c * 32, 256)) =
            make_uint4(pk2(v0.x, v0.y), pk2(v0.z, v0.w), pk2(v1.x, v1.y), pk2(v1.z, v1.w));
        *(uint4*)(nb + swz(r, c * 32 + 16, 256)) =
            make_uint4(pk2(v2.x, v2.y), pk2(v2.z, v2.w), pk2(v3.x, v3.y), pk2(v3.z, v3.w));
    }
    __syncthreads();

    short8 wf[4];
#pragma unroll
    for (int kt = 0; kt < 4; ++kt)
        wf[kt] = *(const short8*)(WN + (wv * 16 + l15) * 128 + kt * 32 + lg * 8);

    f32x4 acc[4];
#pragma unroll
    for (int rt = 0; rt < 4; ++rt) acc[rt] = (f32x4){0.f, 0.f, 0.f, 0.f};
#pragma unroll
    for (int rt = 0; rt < 4; ++rt)
#pragma unroll
        for (int kt = 0; kt < 4; ++kt) {
            short8 axx = *(const short8*)(nb + swz(rt * 16 + l15, kt * 64 + lg * 16, 256));
            acc[rt] = mfma16(axx, wf[kt], acc[rt]);
        }
    float bb = b1[wv * 16 + l15];
#pragma unroll
    for (int rt = 0; rt < 4; ++rt)
#pragma unroll
        for (int j = 0; j < 4; ++j)
            nterm[(b0 + rt * 16 + lg * 4 + j) * 128 + wv * 16 + l15] = acc[rt][j] + bb;
}

// ---------------- FUSED recurrence: GRU | L1 | L2 | dot | AUGRU ----------------
// 512 threads = 8 waves, 16 rows/block, grid 256 (1 block/CU). 54 steps.
// waves_per_eu(2,2): hard 2 waves/EU -> 256 VGPR budget, weights stay resident.
__global__ __attribute__((amdgpu_flat_work_group_size(512, 512),
                          amdgpu_waves_per_eu(2, 2))) void dien_rec(
    const float* __restrict__ inputs, const unsigned short* __restrict__ Wt,
    const unsigned short* __restrict__ Ut, const float* __restrict__ gb,
    const unsigned short* __restrict__ WA, const unsigned short* __restrict__ AW2,
    const float* __restrict__ ab2, const float* __restrict__ nterm,
    const float* __restrict__ W3, const float* __restrict__ b3,
    const unsigned short* __restrict__ Wau, const unsigned short* __restrict__ Uau,
    const float* __restrict__ bp, float* __restrict__ hf)
{
    __shared__ __align__(16) unsigned char WAl[128 * 512];   // 64KB L1 weights swz
    __shared__ __align__(16) unsigned char AW2l[64 * 256];   // 16KB L2 weights swz
    __shared__ __align__(16) unsigned char xbuf[2][4096];
    __shared__ __align__(16) unsigned char hring[5][4096];   // h_t ring (GRU out)
    __shared__ __align__(16) unsigned char pbuf[2][4096];    // h*news
    __shared__ __align__(16) unsigned char a1buf[2][4096];
    __shared__ __align__(16) unsigned char h2buf[2][4096];   // AUGRU hidden
    __shared__ float a2buf[2][16 * 65];
    __shared__ float atsl[16 * 50];
    __shared__ float w3l[64];

    const int tid = threadIdx.x;
    const int wv = tid >> 6, l = tid & 63, l15 = l & 15, lg = l >> 4;
    const size_t row0 = (size_t)blockIdx.x * 16;
    const int ucol = wv * 16 + l15;

    // persistent register weights: GRU + AUGRU
    short8 wf[3][4], uf[3][4], wau[3][4], uau[3][4];
#pragma unroll
    for (int g = 0; g < 3; ++g)
#pragma unroll
        for (int kt = 0; kt < 4; ++kt) {
            int n = g * 128 + ucol;
            int k0 = kt * 32 + lg * 8;
            wf[g][kt]  = *(const short8*)(Wt  + n * 128 + k0);
            uf[g][kt]  = *(const short8*)(Ut  + n * 128 + k0);
            wau[g][kt] = *(const short8*)(Wau + n * 128 + k0);
            uau[g][kt] = *(const short8*)(Uau + n * 128 + k0);
        }
    // L1/L2 weights -> LDS (swizzled)
    for (int i = tid; i < 4096; i += 512) {               // WA: 128 x 256 bf16
        int n = i >> 5, kk = (i & 31) * 8;
        *(short8*)(WAl + n * 512 + ((kk * 2) ^ ((n & 7) << 4))) =
            *(const short8*)(WA + n * 256 + kk);
    }
    for (int i = tid; i < 1024; i += 512) {               // AW2: 64 x 128 bf16
        int n = i >> 4, kk = (i & 15) * 8;
        *(short8*)(AW2l + n * 256 + ((kk * 2) ^ ((n & 7) << 4))) =
            *(const short8*)(AW2 + n * 128 + kk);
    }
    const int n2 = (wv & 3) * 16 + l15;
    const float b2v = (wv < 4) ? ab2[n2] : 0.f;
    const float b3v = b3[0];
    if (tid < 64) w3l[tid] = W3[tid];

    const float bx2 = gb[256 + ucol], bh2 = gb[640 + ucol];
    const float bz  = gb[ucol] + gb[384 + ucol];
    const float br  = gb[128 + ucol] + gb[512 + ucol];
    const float ba0 = bp[ucol], ba1 = bp[128 + ucol], ba2 = bp[256 + ucol];

    float nt4[4], news4[4];
#pragma unroll
    for (int j = 0; j < 4; ++j) {
        int m = lg * 4 + j;
        nt4[j]   = nterm[(row0 + m) * 128 + ucol];
        news4[j] = inputs[((row0 + m) * 51 + 50) * 128 + ucol];
    }

    const int sr = tid >> 5, ss = tid & 31;
    const float* xsrc = inputs + (row0 + sr) * 51 * 128 + ss * 4;

    int rdo[4], wro[4], wafo[8], w2o[4];
#pragma unroll
    for (int kt = 0; kt < 4; ++kt) rdo[kt] = swz(l15, kt * 64 + lg * 16, 256);
#pragma unroll
    for (int j = 0; j < 4; ++j)   wro[j] = swz(lg * 4 + j, ucol * 2, 256);
#pragma unroll
    for (int kt = 0; kt < 8; ++kt)
        wafo[kt] = ucol * 512 + ((kt * 64 + lg * 16) ^ ((ucol & 7) << 4));
#pragma unroll
    for (int kt = 0; kt < 4; ++kt)
        w2o[kt] = n2 * 256 + ((kt * 64 + lg * 16) ^ ((n2 & 7) << 4));
    const int xwo = swz(sr, ss * 8, 256);

    *(uint2*)(hring[4] + tid * 8) = make_uint2(0u, 0u);   // h_{-1} = 0
    *(uint2*)(h2buf[0] + tid * 8) = make_uint2(0u, 0u);   // h2_{-1} = 0
    {
        float4 v = *(const float4*)(xsrc);
        *(uint2*)(xbuf[0] + xwo) = make_uint2(pk2(v.x, v.y), pk2(v.z, v.w));
    }
    float hreg[4]  = {0.f, 0.f, 0.f, 0.f};
    float h2reg[4] = {0.f, 0.f, 0.f, 0.f};
    __syncthreads();

#define STEP(T, PF, DOGRU, DOL1, DOL2, DODOT, DOAU) do {                            \
    const int p_ = (T) & 1;                                                          \
    const int rdslot_ = ((T) + 4) % 5;   /* h_{T-1} */                               \
    const int wrslot_ = (T) % 5;         /* h_T */                                   \
    const int x2slot_ = ((T) + 1) % 5;   /* h_{T-4} */                               \
    float4 xpf_;                                                                     \
    if (PF) xpf_ = *(const float4*)(xsrc + (size_t)((T) + 1) * 128);                 \
    short8 ah_[4];                                                                   \
    if (DOGRU || DOL1) {                                                             \
        _Pragma("unroll")                                                            \
        for (int kt = 0; kt < 4; ++kt)                                               \
            ah_[kt] = *(const short8*)(hring[rdslot_] + rdo[kt]);                    \
    }                                                                                \
    /* ---- GRU step T ---- */                                                       \
    if (DOGRU) {                                                                     \
        short8 ax_[4];                                                               \
        _Pragma("unroll")                                                            \
        for (int kt = 0; kt < 4; ++kt)                                               \
            ax_[kt] = *(const short8*)(xbuf[p_] + rdo[kt]);                          \
        f32x4 accx_[3], acch_[3];                                                    \
        _Pragma("unroll")                                                            \
        for (int g = 0; g < 3; ++g) {                                                \
            accx_[g] = (f32x4){0.f, 0.f, 0.f, 0.f};                                  \
            acch_[g] = (f32x4){0.f, 0.f, 0.f, 0.f};                                  \
        }                                                                            \
        __builtin_amdgcn_s_setprio(1);                                               \
        _Pragma("unroll")                                                            \
        for (int kt = 0; kt < 4; ++kt)                                               \
            _Pragma("unroll")                                                        \
            for (int g = 0; g < 3; ++g) {                                            \
                accx_[g] = mfma16(ax_[kt], wf[g][kt], accx_[g]);                     \
                acch_[g] = mfma16(ah_[kt], uf[g][kt], acch_[g]);                     \
            }                                                                        \
        __builtin_amdgcn_s_setprio(0);                                               \
        _Pragma("unroll")                                                            \
        for (int j = 0; j < 4; ++j) {                                                \
            float z  = sigf(accx_[0][j] + acch_[0][j] + bz);                         \
            float r  = sigf(accx_[1][j] + acch_[1][j] + br);                         \
            float hc = tanhfast(accx_[2][j] + bx2 + r * (acch_[2][j] + bh2));        \
            float hn = fmaf(z, hreg[j] - hc, hc);                                    \
            hreg[j] = hn;                                                            \
            *(unsigned short*)(hring[wrslot_] + wro[j]) = f2bf(hn);                  \
            *(unsigned short*)(pbuf[p_ ^ 1] + wro[j]) = f2bf(hn * news4[j]);         \
        }                                                                            \
    }                                                                                \
    /* ---- attn L1 for T-1 ---- */                                                  \
    if (DOL1) {                                                                      \
        f32x4 lacc_ = (f32x4){0.f, 0.f, 0.f, 0.f};                                   \
        __builtin_amdgcn_s_setprio(1);                                               \
        _Pragma("unroll")                                                            \
        for (int kt = 0; kt < 4; ++kt) {                                             \
            short8 wa_ = *(const short8*)(WAl + wafo[kt]);                           \
            lacc_ = mfma16(ah_[kt], wa_, lacc_);                                     \
        }                                                                            \
        _Pragma("unroll")                                                            \
        for (int kt = 0; kt < 4; ++kt) {                                             \
            short8 pa_ = *(const short8*)(pbuf[p_] + rdo[kt]);                       \
            short8 wa_ = *(const short8*)(WAl + wafo[4 + kt]);                       \
            lacc_ = mfma16(pa_, wa_, lacc_);                                         \
        }                                                                            \
        __builtin_amdgcn_s_setprio(0);                                               \
        _Pragma("unroll")                                                            \
        for (int j = 0; j < 4; ++j) {                                                \
            float v = fmaxf(lacc_[j] + nt4[j], 0.f);                                 \
            *(unsigned short*)(a1buf[p_] + wro[j]) = f2bf(v);                        \
        }                                                                            \
    }                                                                                \
    /* ---- attn L2 for T-2 (waves 0-3) ---- */                                      \
    if (DOL2) {                                                                      \
        if (wv < 4) {                                                                \
            f32x4 c2_ = (f32x4){0.f, 0.f, 0.f, 0.f};                                 \
            _Pragma("unroll")                                                        \
            for (int kt = 0; kt < 4; ++kt) {                                         \
                short8 aa_ = *(const short8*)(a1buf[p_ ^ 1] + rdo[kt]);              \
                short8 w2_ = *(const short8*)(AW2l + w2o[kt]);                       \
                c2_ = mfma16(aa_, w2_, c2_);                                         \
            }                                                                        \
            _Pragma("unroll")                                                        \
            for (int j = 0; j < 4; ++j)                                              \
                a2buf[p_][(lg * 4 + j) * 65 + n2] = fmaxf(c2_[j] + b2v, 0.f);        \
        }                                                                            \
    }                                                                                \
    /* ---- dot for T-3 (waves 4-7) ---- */                                          \
    if (DODOT) {                                                                     \
        if (tid >= 256) {                                                            \
            int rrow_ = (tid - 256) >> 4, cc_ = tid & 15;                            \
            const float* a2r_ = &a2buf[p_ ^ 1][rrow_ * 65];                          \
            float s_ = a2r_[cc_] * w3l[cc_] + a2r_[cc_ + 16] * w3l[cc_ + 16]         \
                     + a2r_[cc_ + 32] * w3l[cc_ + 32] + a2r_[cc_ + 48] * w3l[cc_ + 48];\
            s_ += __shfl_xor(s_, 8, 16);                                             \
            s_ += __shfl_xor(s_, 4, 16);                                             \
            s_ += __shfl_xor(s_, 2, 16);                                             \
            s_ += __shfl_xor(s_, 1, 16);                                             \
            if ((tid & 15) == 0) atsl[rrow_ * 50 + ((T) - 3)] = sigf(s_ + b3v);      \
        }                                                                            \
    }                                                                                \
    /* ---- AUGRU for TA = T-4 ---- */                                               \
    if (DOAU) {                                                                      \
        const int pa2_ = ((T) - 4) & 1;                                              \
        short8 x2_[4], h2_[4];                                                       \
        _Pragma("unroll")                                                            \
        for (int kt = 0; kt < 4; ++kt) {                                             \
            x2_[kt] = *(const short8*)(hring[x2slot_] + rdo[kt]);                    \
            h2_[kt] = *(const short8*)(h2buf[pa2_] + rdo[kt]);                       \
        }                                                                            \
        f32x4 au_x_[3], au_h_[3];                                                    \
        _Pragma("unroll")                                                            \
        for (int g = 0; g < 3; ++g) {                                                \
            au_x_[g] = (f32x4){0.f, 0.f, 0.f, 0.f};                                  \
            au_h_[g] = (f32x4){0.f, 0.f, 0.f, 0.f};                                  \
        }                                                                            \
        __builtin_amdgcn_s_setprio(1);                                               \
        _Pragma("unroll")                                                            \
        for (int kt = 0; kt < 4; ++kt)                                               \
            _Pragma("unroll")                                                        \
            for (int g = 0; g < 3; ++g) {                                            \
                au_x_[g] = mfma16(x2_[kt], wau[g][kt], au_x_[g]);                    \
                au_h_[g] = mfma16(h2_[kt], uau[g][kt], au_h_[g]);                    \
            }                                                                        \
        __builtin_amdgcn_s_setprio(0);                                               \
        _Pragma("unroll")                                                            \
        for (int j = 0; j < 4; ++j) {                                                \
            int m = lg * 4 + j;                                                      \
            float u  = sigf(au_x_[0][j] + ba0 + au_h_[0][j]);                        \
            float r  = sigf(au_x_[1][j] + ba1 + au_h_[1][j]);                        \
            float c  = tanhfast(au_x_[2][j] + ba2 + r * au_h_[2][j]);                \
            float uu = atsl[m * 50 + ((T) - 4)] * u;                                 \
            float hn = fmaf(uu, c - h2reg[j], h2reg[j]);                             \
            h2reg[j] = hn;                                                           \
            *(unsigned short*)(h2buf[pa2_ ^ 1] + wro[j]) = f2bf(hn);                 \
        }                                                                            \
    }                                                                                \
    if (PF)                                                                          \
        *(uint2*)(xbuf[p_ ^ 1] + xwo) =                                              \
            make_uint2(pk2(xpf_.x, xpf_.y), pk2(xpf_.z, xpf_.w));                    \
    barrier_lds();                                                                   \
} while (0)

    STEP(0, 1, 1, 0, 0, 0, 0);
    STEP(1, 1, 1, 1, 0, 0, 0);
    STEP(2, 1, 1, 1, 1, 0, 0);
    STEP(3, 1, 1, 1, 1, 1, 0);
    for (int t = 4; t <= 48; ++t) STEP(t, 1, 1, 1, 1, 1, 1);
    STEP(49, 0, 1, 1, 1, 1, 1);
    STEP(50, 0, 0, 1, 1, 1, 1);
    STEP(51, 0, 0, 0, 1, 1, 1);
    STEP(52, 0, 0, 0, 0, 1, 1);
    STEP(53, 0, 0, 0, 0, 0, 1);
#undef STEP

#pragma unroll
    for (int j = 0; j < 4; ++j)
        hf[(row0 + lg * 4 + j) * 128 + ucol] = h2reg[j];
}

// ---------------- final: BN + 256->256->128->1, MFMA ----------------
__global__ __launch_bounds__(256, 2) void final_mfma(
    const float* __restrict__ hfv, const float* __restrict__ inputs,
    const float* __restrict__ gam, const float* __restrict__ bet,
    const float* __restrict__ mu, const float* __restrict__ var,
    const unsigned short* __restrict__ W1t, const float* __restrict__ b1,
    const unsigned short* __restrict__ W2t, const float* __restrict__ b2,
    const float* __restrict__ fW, const float* __restrict__ fb,
    float* __restrict__ out)
{
    __shared__ __align__(16) unsigned char xnb[16 * 512];
    __shared__ __align__(16) unsigned char d1b[16 * 512];
    __shared__ float d2b[16 * 132];
    __shared__ float wfl[128];

    const int tid = threadIdx.x;
    const int wv = tid >> 6, l = tid & 63, l15 = l & 15, lg = l >> 4;
    const size_t r0 = (size_t)blockIdx.x * 16;

    short8 w1f[4][8];
#pragma unroll
    for (int p = 0; p < 4; ++p)
#pragma unroll
        for (int kt = 0; kt < 8; ++kt) {
            int n = wv * 64 + p * 16 + l15;
            w1f[p][kt] = *(const short8*)(W1t + n * 256 + kt * 32 + lg * 8);
        }
    short8 w2f[2][8];
#pragma unroll
    for (int p = 0; p < 2; ++p)
#pragma unroll
        for (int kt = 0; kt < 8; ++kt) {
            int n = wv * 32 + p * 16 + l15;
            w2f[p][kt] = *(const short8*)(W2t + n * 256 + kt * 32 + lg * 8);
        }
    if (tid < 128) wfl[tid] = fW[tid];

    {
        int r = tid >> 4, c = tid & 15, k0 = c * 16;
        float v[16];
#pragma unroll
        for (int q = 0; q < 16; ++q) {
            int k = k0 + q;
            float x = (k < 128) ? hfv[(r0 + r) * 128 + k]
                                : inputs[((r0 + r) * 51 + 50) * 128 + (k - 128)];
            float s = gam[k] * rsqrtf(var[k] + 0.001f);
            v[q] = (x - mu[k]) * s + bet[k];
        }
        *(uint4*)(xnb + swz(r, k0 * 2, 512)) =
            make_uint4(pk2(v[0], v[1]), pk2(v[2], v[3]), pk2(v[4], v[5]), pk2(v[6], v[7]));
        *(uint4*)(xnb + swz(r, k0 * 2 + 16, 512)) =
            make_uint4(pk2(v[8], v[9]), pk2(v[10], v[11]), pk2(v[12], v[13]), pk2(v[14], v[15]));
    }
    __syncthreads();

    f32x4 a1[4];
#pragma unroll
    for (int p = 0; p < 4; ++p) a1[p] = (f32x4){0.f, 0.f, 0.f, 0.f};
#pragma unroll
    for (int kt = 0; kt < 8; ++kt) {
        short8 axx = *(const short8*)(xnb + swz(l15, kt * 64 + lg * 16, 512));
#pragma unroll
        for (int p = 0; p < 4; ++p) a1[p] = mfma16(axx, w1f[p][kt], a1[p]);
    }
#pragma unroll
    for (int p = 0; p < 4; ++p) {
        float bb = b1[wv * 64 + p * 16 + l15];
#pragma unroll
        for (int j = 0; j < 4; ++j) {
            int row = lg * 4 + j, col = wv * 64 + p * 16 + l15;
            *(unsigned short*)(d1b + swz(row, col * 2, 512)) = f2bf(lky(a1[p][j] + bb));
        }
    }
    __syncthreads();

    f32x4 a2[2];
#pragma unroll
    for (int p = 0; p < 2; ++p) a2[p] = (f32x4){0.f, 0.f, 0.f, 0.f};
#pragma unroll
    for (int kt = 0; kt < 8; ++kt) {
        short8 axx = *(const short8*)(d1b + swz(l15, kt * 64 + lg * 16, 512));
#pragma unroll
        for (int p = 0; p < 2; ++p) a2[p] = mfma16(axx, w2f[p][kt], a2[p]);
    }
#pragma unroll
    for (int p = 0; p < 2; ++p) {
        float bb = b2[wv * 32 + p * 16 + l15];
#pragma unroll
        for (int j = 0; j < 4; ++j)
            d2b[(lg * 4 + j) * 132 + wv * 32 + p * 16 + l15] = lky(a2[p][j] + bb);
    }
    __syncthreads();

    if (tid < 16) {
        float s = fb[0];
#pragma unroll 8
        for (int k = 0; k < 128; ++k) s += d2b[tid * 132 + k] * wfl[k];
        out[r0 + tid] = sigf(s);
    }
}

extern "C" void kernel_launch(void* const* d_in, const int* in_sizes, int n_in,
                              void* d_out, int out_size, void* d_ws, size_t ws_size,
                              hipStream_t stream)
{
    const float* inputs   = (const float*)d_in[0];
    const float* gru_W    = (const float*)d_in[1];
    const float* gru_U    = (const float*)d_in[2];
    const float* gru_b    = (const float*)d_in[3];
    const float* att_W1   = (const float*)d_in[4];
    const float* att_b1   = (const float*)d_in[5];
    const float* att_W2   = (const float*)d_in[6];
    const float* att_b2   = (const float*)d_in[7];
    const float* att_W3   = (const float*)d_in[8];
    const float* att_b3   = (const float*)d_in[9];
    const float* au_Wu    = (const float*)d_in[10];
    const float* au_bu    = (const float*)d_in[11];
    const float* au_Uu    = (const float*)d_in[12];
    const float* au_Wr    = (const float*)d_in[13];
    const float* au_br    = (const float*)d_in[14];
    const float* au_Ur    = (const float*)d_in[15];
    const float* au_Wc    = (const float*)d_in[16];
    const float* au_bc    = (const float*)d_in[17];
    const float* au_Uc    = (const float*)d_in[18];
    const float* bn_gamma = (const float*)d_in[19];
    const float* bn_beta  = (const float*)d_in[20];
    const float* bn_mean  = (const float*)d_in[21];
    const float* bn_var   = (const float*)d_in[22];
    const float* d_W1     = (const float*)d_in[23];
    const float* d_b1     = (const float*)d_in[24];
    const float* d_W2     = (const float*)d_in[25];
    const float* d_b2     = (const float*)d_in[26];
    const float* f_W      = (const float*)d_in[27];
    const float* f_b      = (const float*)d_in[28];

    char* w = (char*)d_ws;
    float* hf           = (float*)(w + 53248000);
    float* nterm        = (float*)(w + 55345152);
    unsigned short* Wg  = (unsigned short*)(w + 57442304);
    unsigned short* Ug  = (unsigned short*)(w + 57540608);
    unsigned short* Wau = (unsigned short*)(w + 57638912);
    unsigned short* Uau = (unsigned short*)(w + 57737216);
    unsigned short* WA  = (unsigned short*)(w + 57835520);
    unsigned short* WN  = (unsigned short*)(w + 57901056);
    unsigned short* AW2 = (unsigned short*)(w + 57933824);
    unsigned short* DW1 = (unsigned short*)(w + 57950208);
    unsigned short* DW2 = (unsigned short*)(w + 58081280);
    float* bp           = (float*)(w + 58146816);

    pack_all<<<994, 256, 0, stream>>>(
        gru_W, gru_U, au_Wu, au_Wr, au_Wc, au_Uu, au_Ur, au_Uc,
        att_W1, att_W2, d_W1, d_W2, au_bu, au_br, au_bc,
        Wg, Ug, Wau, Uau, WA, WN, AW2, DW1, DW2, bp);
    nterm_kernel<<<64, 512, 0, stream>>>(inputs, WN, att_b1, nterm);
    dien_rec<<<256, 512, 0, stream>>>(inputs, Wg, Ug, gru_b, WA, AW2, att_b2,
                                      nterm, att_W3, att_b3, Wau, Uau, bp, hf);
    final_mfma<<<256, 256, 0, stream>>>(hf, inputs, bn_gamma, bn_beta, bn_mean, bn_var,
                                        DW1, d_b1, DW2, d_b2, f_W, f_b, (float*)d_out);
}

// Round 15
// 166.905 us; speedup vs baseline: 2.1938x; 2.1938x over previous
//
#include <hip/hip_runtime.h>
#include <hip/hip_bf16.h>
#include <math.h>

// DIEN bf16-MFMA v13 == v9/r11 revert (best verified config, 167.1 us):
// split gru_attn + augru recurrences, 16 rows/block, grid 256, one
// lgkmcnt-only barrier per step, branch-free steady-state, MFMA clustering,
// packed hs4 uint2 layout, a2buf stride 65, dot on waves 4-7.
// Fused single-kernel variants (r12-r14) proven register-infeasible
// (allocator pins 128 VGPR; weight remat 300MB/step-loop). ws layout unchanged.

#define LK 0.0003f

typedef __attribute__((ext_vector_type(8))) short short8;
typedef __attribute__((ext_vector_type(4))) float f32x4;

__device__ __forceinline__ float sigf(float x) {
    return __builtin_amdgcn_rcpf(1.0f + __expf(-x));
}
__device__ __forceinline__ float tanhfast(float x) {
    return fmaf(2.0f, __builtin_amdgcn_rcpf(1.0f + __expf(-2.0f * x)), -1.0f);
}
__device__ __forceinline__ float lky(float v) { return v >= 0.0f ? v : LK * v; }
__device__ __forceinline__ unsigned short f2bf(float f) {
    __bf16 b = (__bf16)f;
    return *reinterpret_cast<unsigned short*>(&b);
}
__device__ __forceinline__ unsigned pk2(float a, float b) {
    return (unsigned)f2bf(a) | ((unsigned)f2bf(b) << 16);
}
__device__ __forceinline__ int swz(int row, int kbyte, int stride) {
    return row * stride + (kbyte ^ ((row & 7) << 4));
}
__device__ __forceinline__ f32x4 mfma16(short8 a, short8 b, f32x4 c) {
    return __builtin_amdgcn_mfma_f32_16x16x32_bf16(a, b, c, 0, 0, 0);
}
// Barrier that waits only on LDS ops (global stores here have no intra-kernel
// reader; loads are drained at their uses by compiler-inserted vmcnt).
__device__ __forceinline__ void barrier_lds() {
    __builtin_amdgcn_sched_barrier(0);
    asm volatile("s_waitcnt lgkmcnt(0)" ::: "memory");
    __builtin_amdgcn_sched_barrier(0);
    __builtin_amdgcn_s_barrier();
    __builtin_amdgcn_sched_barrier(0);
}

// ---------------- pack & transpose all weights to bf16 [n][k] panels ----------------
__global__ void pack_all(
    const float* __restrict__ gW, const float* __restrict__ gU,
    const float* __restrict__ aWu, const float* __restrict__ aWr, const float* __restrict__ aWc,
    const float* __restrict__ aUu, const float* __restrict__ aUr, const float* __restrict__ aUc,
    const float* __restrict__ tW1, const float* __restrict__ tW2,
    const float* __restrict__ dW1, const float* __restrict__ dW2,
    const float* __restrict__ abu, const float* __restrict__ abr, const float* __restrict__ abc,
    unsigned short* __restrict__ Wg, unsigned short* __restrict__ Ug,
    unsigned short* __restrict__ Wau, unsigned short* __restrict__ Uau,
    unsigned short* __restrict__ WA, unsigned short* __restrict__ WN,
    unsigned short* __restrict__ AW2,
    unsigned short* __restrict__ DW1, unsigned short* __restrict__ DW2,
    float* __restrict__ bp)
{
    int i = blockIdx.x * 256 + threadIdx.x;
    if (i < 49152) {
        int n = i >> 7, k = i & 127;
        Wg[i] = f2bf(gW[k * 384 + n]);
        Ug[i] = f2bf(gU[k * 384 + n]);
    } else if (i < 98304) {
        int j = i - 49152; int n = j >> 7, k = j & 127;
        int g = n >> 7, c = n & 127;
        const float* s = (g == 0) ? aWu : (g == 1) ? aWr : aWc;
        const float* u = (g == 0) ? aUu : (g == 1) ? aUr : aUc;
        Wau[j] = f2bf(s[k * 128 + c]);
        Uau[j] = f2bf(u[k * 128 + c]);
    } else if (i < 131072) {
        int j = i - 98304; int n = j >> 8, k = j & 255;
        float v = (k < 128) ? (tW1[k * 128 + n] - tW1[(128 + k) * 128 + n])
                            : tW1[(384 + (k - 128)) * 128 + n];
        WA[j] = f2bf(v);
    } else if (i < 147456) {
        int j = i - 131072; int n = j >> 7, k = j & 127;
        WN[j] = f2bf(tW1[(128 + k) * 128 + n] + tW1[(256 + k) * 128 + n]);
    } else if (i < 155648) {
        int j = i - 147456; int n = j >> 7, k = j & 127;
        AW2[j] = f2bf(tW2[k * 64 + n]);
    } else if (i < 221184) {
        int j = i - 155648; int n = j >> 8, k = j & 255;
        DW1[j] = f2bf(dW1[k * 256 + n]);
    } else if (i < 253952) {
        int j = i - 221184; int n = j >> 8, k = j & 255;
        DW2[j] = f2bf(dW2[k * 128 + n]);
    } else if (i < 254336) {
        int j = i - 253952;
        bp[j] = (j < 128) ? abu[j] : (j < 256) ? abr[j - 128] : abc[j - 256];
    }
}

// ---------------- nterm = news @ WN + b1 ----------------
__global__ __launch_bounds__(512, 2) void nterm_kernel(
    const float* __restrict__ inputs, const unsigned short* __restrict__ WN,
    const float* __restrict__ b1, float* __restrict__ nterm)
{
    __shared__ __align__(16) unsigned char nb[64 * 256];

    const int tid = threadIdx.x;
    const int wv = tid >> 6, l = tid & 63, l15 = l & 15, lg = l >> 4;
    const size_t b0 = (size_t)blockIdx.x * 64;

    {
        int r = tid >> 3, c = tid & 7;
        const float* src = inputs + ((b0 + r) * 51 + 50) * 128 + c * 16;
        float4 v0 = *(const float4*)(src);
        float4 v1 = *(const float4*)(src + 4);
        float4 v2 = *(const float4*)(src + 8);
        float4 v3 = *(const float4*)(src + 12);
        *(uint4*)(nb + swz(r, c * 32, 256)) =
            make_uint4(pk2(v0.x, v0.y), pk2(v0.z, v0.w), pk2(v1.x, v1.y), pk2(v1.z, v1.w));
        *(uint4*)(nb + swz(r, c * 32 + 16, 256)) =
            make_uint4(pk2(v2.x, v2.y), pk2(v2.z, v2.w), pk2(v3.x, v3.y), pk2(v3.z, v3.w));
    }
    __syncthreads();

    short8 wf[4];
#pragma unroll
    for (int kt = 0; kt < 4; ++kt)
        wf[kt] = *(const short8*)(WN + (wv * 16 + l15) * 128 + kt * 32 + lg * 8);

    f32x4 acc[4];
#pragma unroll
    for (int rt = 0; rt < 4; ++rt) acc[rt] = (f32x4){0.f, 0.f, 0.f, 0.f};
#pragma unroll
    for (int rt = 0; rt < 4; ++rt)
#pragma unroll
        for (int kt = 0; kt < 4; ++kt) {
            short8 axx = *(const short8*)(nb + swz(rt * 16 + l15, kt * 64 + lg * 16, 256));
            acc[rt] = mfma16(axx, wf[kt], acc[rt]);
        }
    float bb = b1[wv * 16 + l15];
#pragma unroll
    for (int rt = 0; rt < 4; ++rt)
#pragma unroll
        for (int j = 0; j < 4; ++j)
            nterm[(b0 + rt * 16 + lg * 4 + j) * 128 + wv * 16 + l15] = acc[rt][j] + bb;
}

// ---------------- GRU + attention fused persistent recurrence ----------------
__global__ __launch_bounds__(512, 2) void gru_attn(
    const float* __restrict__ inputs, const unsigned short* __restrict__ Wt,
    const unsigned short* __restrict__ Ut, const float* __restrict__ gb,
    const unsigned short* __restrict__ WA, const unsigned short* __restrict__ AW2,
    const float* __restrict__ ab2, const float* __restrict__ nterm,
    const float* __restrict__ W3, const float* __restrict__ b3,
    uint2* __restrict__ hs4, float* __restrict__ ats)
{
    __shared__ __align__(16) unsigned char xbuf[2][4096];
    __shared__ __align__(16) unsigned char hbuf[2][4096];
    __shared__ __align__(16) unsigned char pbuf[2][4096];
    __shared__ __align__(16) unsigned char a1buf[2][4096];
    __shared__ float a2buf[2][16 * 65];
    __shared__ float w3l[64];

    const int tid = threadIdx.x;
    const int wv = tid >> 6, l = tid & 63, l15 = l & 15, lg = l >> 4;
    const size_t row0 = (size_t)blockIdx.x * 16;
    const int ucol = wv * 16 + l15;

    short8 wf[3][4], uf[3][4];
#pragma unroll
    for (int g = 0; g < 3; ++g)
#pragma unroll
        for (int kt = 0; kt < 4; ++kt) {
            int n = g * 128 + ucol;
            int k0 = kt * 32 + lg * 8;
            wf[g][kt] = *(const short8*)(Wt + n * 128 + k0);
            uf[g][kt] = *(const short8*)(Ut + n * 128 + k0);
        }
    short8 waf[8];
#pragma unroll
    for (int kt = 0; kt < 8; ++kt)
        waf[kt] = *(const short8*)(WA + ucol * 256 + kt * 32 + lg * 8);
    short8 w2f[4];
    const int n2 = (wv & 3) * 16 + l15;
    if (wv < 4) {
#pragma unroll
        for (int kt = 0; kt < 4; ++kt)
            w2f[kt] = *(const short8*)(AW2 + n2 * 128 + kt * 32 + lg * 8);
    }
    const float b2v = (wv < 4) ? ab2[n2] : 0.f;
    const float b3v = b3[0];
    if (tid < 64) w3l[tid] = W3[tid];

    const float bx2 = gb[256 + ucol], bh2 = gb[640 + ucol];
    const float bz  = gb[ucol] + gb[384 + ucol];
    const float br  = gb[128 + ucol] + gb[512 + ucol];

    float nt4[4], news4[4];
#pragma unroll
    for (int j = 0; j < 4; ++j) {
        int m = lg * 4 + j;
        nt4[j]   = nterm[(row0 + m) * 128 + ucol];
        news4[j] = inputs[((row0 + m) * 51 + 50) * 128 + ucol];
    }
    uint2* hs4p = hs4 + ((row0 >> 2) + lg) * 6400 + ucol;

    const int sr = tid >> 5, ss = tid & 31;
    const float* xsrc = inputs + (row0 + sr) * 51 * 128 + ss * 4;

    int rdo[4], wro[4];
#pragma unroll
    for (int kt = 0; kt < 4; ++kt) rdo[kt] = swz(l15, kt * 64 + lg * 16, 256);
#pragma unroll
    for (int j = 0; j < 4; ++j)   wro[j] = swz(lg * 4 + j, ucol * 2, 256);
    const int xwo = swz(sr, ss * 8, 256);

    *(uint2*)(hbuf[0] + tid * 8) = make_uint2(0u, 0u);
    {
        float4 v = *(const float4*)(xsrc);
        *(uint2*)(xbuf[0] + xwo) = make_uint2(pk2(v.x, v.y), pk2(v.z, v.w));
    }
    float hreg[4] = {0.f, 0.f, 0.f, 0.f};
    __syncthreads();

#define STEP(T, PF, DOGRU, DOL1, DOL2, DODOT) do {                                  \
    const int p_ = (T) & 1;                                                          \
    float4 xpf_;                                                                     \
    if (PF) xpf_ = *(const float4*)(xsrc + (size_t)((T) + 1) * 128);                 \
    short8 ah_[4];                                                                   \
    if (DOGRU || DOL1) {                                                             \
        _Pragma("unroll")                                                            \
        for (int kt = 0; kt < 4; ++kt)                                               \
            ah_[kt] = *(const short8*)(hbuf[p_] + rdo[kt]);                          \
    }                                                                                \
    short8 ax_[4], pa_[4];                                                           \
    if (DOGRU) {                                                                     \
        _Pragma("unroll")                                                            \
        for (int kt = 0; kt < 4; ++kt)                                               \
            ax_[kt] = *(const short8*)(xbuf[p_] + rdo[kt]);                          \
    }                                                                                \
    if (DOL1) {                                                                      \
        _Pragma("unroll")                                                            \
        for (int kt = 0; kt < 4; ++kt)                                               \
            pa_[kt] = *(const short8*)(pbuf[p_] + rdo[kt]);                          \
    }                                                                                \
    f32x4 accx_[3], acch_[3], lacc_;                                                 \
    __builtin_amdgcn_s_setprio(1);                                                   \
    if (DOGRU) {                                                                     \
        _Pragma("unroll")                                                            \
        for (int g = 0; g < 3; ++g) {                                                \
            accx_[g] = (f32x4){0.f, 0.f, 0.f, 0.f};                                  \
            acch_[g] = (f32x4){0.f, 0.f, 0.f, 0.f};                                  \
        }                                                                            \
        _Pragma("unroll")                                                            \
        for (int kt = 0; kt < 4; ++kt)                                               \
            _Pragma("unroll")                                                        \
            for (int g = 0; g < 3; ++g) {                                            \
                accx_[g] = mfma16(ax_[kt], wf[g][kt], accx_[g]);                     \
                acch_[g] = mfma16(ah_[kt], uf[g][kt], acch_[g]);                     \
            }                                                                        \
    }                                                                                \
    if (DOL1) {                                                                      \
        lacc_ = (f32x4){0.f, 0.f, 0.f, 0.f};                                         \
        _Pragma("unroll")                                                            \
        for (int kt = 0; kt < 4; ++kt) lacc_ = mfma16(ah_[kt], waf[kt], lacc_);      \
        _Pragma("unroll")                                                            \
        for (int kt = 0; kt < 4; ++kt) lacc_ = mfma16(pa_[kt], waf[4 + kt], lacc_);  \
    }                                                                                \
    __builtin_amdgcn_s_setprio(0);                                                   \
    if (DOGRU) {                                                                     \
        unsigned short hbv_[4];                                                      \
        _Pragma("unroll")                                                            \
        for (int j = 0; j < 4; ++j) {                                                \
            float z  = sigf(accx_[0][j] + acch_[0][j] + bz);                         \
            float r  = sigf(accx_[1][j] + acch_[1][j] + br);                         \
            float hc = tanhfast(accx_[2][j] + bx2 + r * (acch_[2][j] + bh2));        \
            float hn = fmaf(z, hreg[j] - hc, hc);                                    \
            hreg[j] = hn;                                                            \
            hbv_[j] = f2bf(hn);                                                      \
            *(unsigned short*)(hbuf[p_ ^ 1] + wro[j]) = hbv_[j];                     \
            *(unsigned short*)(pbuf[p_ ^ 1] + wro[j]) = f2bf(hn * news4[j]);         \
        }                                                                            \
        hs4p[(size_t)(T) * 128] =                                                    \
            make_uint2((unsigned)hbv_[0] | ((unsigned)hbv_[1] << 16),                \
                       (unsigned)hbv_[2] | ((unsigned)hbv_[3] << 16));               \
    }                                                                                \
    if (DOL1) {                                                                      \
        _Pragma("unroll")                                                            \
        for (int j = 0; j < 4; ++j) {                                                \
            float v = fmaxf(lacc_[j] + nt4[j], 0.f);                                 \
            *(unsigned short*)(a1buf[p_] + wro[j]) = f2bf(v);                        \
        }                                                                            \
    }                                                                                \
    if (DOL2) {                                                                      \
        if (wv < 4) {                                                                \
            f32x4 c2_ = (f32x4){0.f, 0.f, 0.f, 0.f};                                 \
            _Pragma("unroll")                                                        \
            for (int kt = 0; kt < 4; ++kt) {                                         \
                short8 aa_ = *(const short8*)(a1buf[p_ ^ 1] + rdo[kt]);              \
                c2_ = mfma16(aa_, w2f[kt], c2_);                                     \
            }                                                                        \
            _Pragma("unroll")                                                        \
            for (int j = 0; j < 4; ++j)                                              \
                a2buf[p_][(lg * 4 + j) * 65 + n2] = fmaxf(c2_[j] + b2v, 0.f);        \
        }                                                                            \
    }                                                                                \
    if (DODOT) {                                                                     \
        if (tid >= 256) {  /* waves 4-7: 16 rows x 16 lanes */                       \
            int rrow_ = (tid - 256) >> 4, cc_ = tid & 15;                            \
            const float* a2r_ = &a2buf[p_ ^ 1][rrow_ * 65];                          \
            float s_ = a2r_[cc_] * w3l[cc_] + a2r_[cc_ + 16] * w3l[cc_ + 16]         \
                     + a2r_[cc_ + 32] * w3l[cc_ + 32] + a2r_[cc_ + 48] * w3l[cc_ + 48];\
            s_ += __shfl_xor(s_, 8, 16);                                             \
            s_ += __shfl_xor(s_, 4, 16);                                             \
            s_ += __shfl_xor(s_, 2, 16);                                             \
            s_ += __shfl_xor(s_, 1, 16);                                             \
            if ((tid & 15) == 0)                                                     \
                ats[(row0 + rrow_) * 50 + ((T) - 3)] = sigf(s_ + b3v);               \
        }                                                                            \
    }                                                                                \
    if (PF)                                                                          \
        *(uint2*)(xbuf[p_ ^ 1] + xwo) =                                              \
            make_uint2(pk2(xpf_.x, xpf_.y), pk2(xpf_.z, xpf_.w));                    \
    barrier_lds();                                                                   \
} while (0)

    STEP(0, 1, 1, 0, 0, 0);
    STEP(1, 1, 1, 1, 0, 0);
    STEP(2, 1, 1, 1, 1, 0);
    for (int t = 3; t <= 48; ++t) STEP(t, 1, 1, 1, 1, 1);
    STEP(49, 0, 1, 1, 1, 1);
    STEP(50, 0, 0, 1, 1, 1);
    STEP(51, 0, 0, 0, 1, 1);
    STEP(52, 0, 0, 0, 0, 1);
#undef STEP
}

// ---------------- AUGRU: MFMA recurrence, lgkmcnt-only barrier ----------------
__global__ __launch_bounds__(512, 2) void augru_mfma(
    const uint2* __restrict__ hs4, const unsigned short* __restrict__ Wt,
    const unsigned short* __restrict__ Ut, const float* __restrict__ bp,
    const float* __restrict__ ats, float* __restrict__ hf)
{
    __shared__ __align__(16) unsigned char xbuf[2][4096];
    __shared__ __align__(16) unsigned char hbuf[2][4096];
    __shared__ float atsl[16 * 50];

    const int tid = threadIdx.x;
    const int wv = tid >> 6, l = tid & 63, l15 = l & 15, lg = l >> 4;
    const size_t row0 = (size_t)blockIdx.x * 16;
    const int ucol = wv * 16 + l15;

    short8 wf[3][4], uf[3][4];
#pragma unroll
    for (int g = 0; g < 3; ++g)
#pragma unroll
        for (int kt = 0; kt < 4; ++kt) {
            int n = g * 128 + ucol;
            int k0 = kt * 32 + lg * 8;
            wf[g][kt] = *(const short8*)(Wt + n * 128 + k0);
            uf[g][kt] = *(const short8*)(Ut + n * 128 + k0);
        }
    const float bx0 = bp[ucol], bx1 = bp[128 + ucol], bx2 = bp[256 + ucol];

    const int sg = tid >> 7, sc = tid & 127;
    const uint2* xsrc2 = hs4 + ((row0 >> 2) + sg) * 6400 + sc;

    int rdo[4], wro[4];
#pragma unroll
    for (int kt = 0; kt < 4; ++kt) rdo[kt] = swz(l15, kt * 64 + lg * 16, 256);
#pragma unroll
    for (int j = 0; j < 4; ++j)   wro[j] = swz(lg * 4 + j, ucol * 2, 256);
    int xwo4[4];
#pragma unroll
    for (int q = 0; q < 4; ++q)   xwo4[q] = swz(4 * sg + q, sc * 2, 256);

    *(uint2*)(hbuf[0] + tid * 8) = make_uint2(0u, 0u);
    if (tid < 400) {
        atsl[tid] = ats[row0 * 50 + tid];
        atsl[tid + 400] = ats[row0 * 50 + tid + 400];
    }
    {
        uint2 u = xsrc2[0];
        *(unsigned short*)(xbuf[0] + xwo4[0]) = (unsigned short)(u.x & 0xffff);
        *(unsigned short*)(xbuf[0] + xwo4[1]) = (unsigned short)(u.x >> 16);
        *(unsigned short*)(xbuf[0] + xwo4[2]) = (unsigned short)(u.y & 0xffff);
        *(unsigned short*)(xbuf[0] + xwo4[3]) = (unsigned short)(u.y >> 16);
    }
    float hreg[4] = {0.f, 0.f, 0.f, 0.f};
    __syncthreads();

    for (int t = 0; t < 50; ++t) {
        const int p = t & 1;
        uint2 xnext;
        if (t < 49) xnext = xsrc2[(size_t)(t + 1) * 128];

        short8 ax[4], ah[4];
#pragma unroll
        for (int kt = 0; kt < 4; ++kt) {
            ax[kt] = *(const short8*)(xbuf[p] + rdo[kt]);
            ah[kt] = *(const short8*)(hbuf[p] + rdo[kt]);
        }
        f32x4 accx[3], acch[3];
#pragma unroll
        for (int g = 0; g < 3; ++g) {
            accx[g] = (f32x4){0.f, 0.f, 0.f, 0.f};
            acch[g] = (f32x4){0.f, 0.f, 0.f, 0.f};
        }
        __builtin_amdgcn_s_setprio(1);
#pragma unroll
        for (int kt = 0; kt < 4; ++kt)
#pragma unroll
            for (int g = 0; g < 3; ++g) {
                accx[g] = mfma16(ax[kt], wf[g][kt], accx[g]);
                acch[g] = mfma16(ah[kt], uf[g][kt], acch[g]);
            }
        __builtin_amdgcn_s_setprio(0);
#pragma unroll
        for (int j = 0; j < 4; ++j) {
            int m = lg * 4 + j;
            float u  = sigf(accx[0][j] + bx0 + acch[0][j]);
            float r  = sigf(accx[1][j] + bx1 + acch[1][j]);
            float c  = tanhfast(accx[2][j] + bx2 + r * acch[2][j]);
            float uu = atsl[m * 50 + t] * u;
            float hn = fmaf(uu, c - hreg[j], hreg[j]);
            hreg[j] = hn;
            *(unsigned short*)(hbuf[p ^ 1] + wro[j]) = f2bf(hn);
        }
        if (t < 49) {
            *(unsigned short*)(xbuf[p ^ 1] + xwo4[0]) = (unsigned short)(xnext.x & 0xffff);
            *(unsigned short*)(xbuf[p ^ 1] + xwo4[1]) = (unsigned short)(xnext.x >> 16);
            *(unsigned short*)(xbuf[p ^ 1] + xwo4[2]) = (unsigned short)(xnext.y & 0xffff);
            *(unsigned short*)(xbuf[p ^ 1] + xwo4[3]) = (unsigned short)(xnext.y >> 16);
        }
        barrier_lds();
    }
#pragma unroll
    for (int j = 0; j < 4; ++j)
        hf[(row0 + lg * 4 + j) * 128 + ucol] = hreg[j];
}

// ---------------- final: BN + 256->256->128->1, MFMA ----------------
__global__ __launch_bounds__(256, 2) void final_mfma(
    const float* __restrict__ hfv, const float* __restrict__ inputs,
    const float* __restrict__ gam, const float* __restrict__ bet,
    const float* __restrict__ mu, const float* __restrict__ var,
    const unsigned short* __restrict__ W1t, const float* __restrict__ b1,
    const unsigned short* __restrict__ W2t, const float* __restrict__ b2,
    const float* __restrict__ fW, const float* __restrict__ fb,
    float* __restrict__ out)
{
    __shared__ __align__(16) unsigned char xnb[16 * 512];
    __shared__ __align__(16) unsigned char d1b[16 * 512];
    __shared__ float d2b[16 * 132];
    __shared__ float wfl[128];

    const int tid = threadIdx.x;
    const int wv = tid >> 6, l = tid & 63, l15 = l & 15, lg = l >> 4;
    const size_t r0 = (size_t)blockIdx.x * 16;

    short8 w1f[4][8];
#pragma unroll
    for (int p = 0; p < 4; ++p)
#pragma unroll
        for (int kt = 0; kt < 8; ++kt) {
            int n = wv * 64 + p * 16 + l15;
            w1f[p][kt] = *(const short8*)(W1t + n * 256 + kt * 32 + lg * 8);
        }
    short8 w2f[2][8];
#pragma unroll
    for (int p = 0; p < 2; ++p)
#pragma unroll
        for (int kt = 0; kt < 8; ++kt) {
            int n = wv * 32 + p * 16 + l15;
            w2f[p][kt] = *(const short8*)(W2t + n * 256 + kt * 32 + lg * 8);
        }
    if (tid < 128) wfl[tid] = fW[tid];

    {
        int r = tid >> 4, c = tid & 15, k0 = c * 16;
        float v[16];
#pragma unroll
        for (int q = 0; q < 16; ++q) {
            int k = k0 + q;
            float x = (k < 128) ? hfv[(r0 + r) * 128 + k]
                                : inputs[((r0 + r) * 51 + 50) * 128 + (k - 128)];
            float s = gam[k] * rsqrtf(var[k] + 0.001f);
            v[q] = (x - mu[k]) * s + bet[k];
        }
        *(uint4*)(xnb + swz(r, k0 * 2, 512)) =
            make_uint4(pk2(v[0], v[1]), pk2(v[2], v[3]), pk2(v[4], v[5]), pk2(v[6], v[7]));
        *(uint4*)(xnb + swz(r, k0 * 2 + 16, 512)) =
            make_uint4(pk2(v[8], v[9]), pk2(v[10], v[11]), pk2(v[12], v[13]), pk2(v[14], v[15]));
    }
    __syncthreads();

    f32x4 a1[4];
#pragma unroll
    for (int p = 0; p < 4; ++p) a1[p] = (f32x4){0.f, 0.f, 0.f, 0.f};
#pragma unroll
    for (int kt = 0; kt < 8; ++kt) {
        short8 axx = *(const short8*)(xnb + swz(l15, kt * 64 + lg * 16, 512));
#pragma unroll
        for (int p = 0; p < 4; ++p) a1[p] = mfma16(axx, w1f[p][kt], a1[p]);
    }
#pragma unroll
    for (int p = 0; p < 4; ++p) {
        float bb = b1[wv * 64 + p * 16 + l15];
#pragma unroll
        for (int j = 0; j < 4; ++j) {
            int row = lg * 4 + j, col = wv * 64 + p * 16 + l15;
            *(unsigned short*)(d1b + swz(row, col * 2, 512)) = f2bf(lky(a1[p][j] + bb));
        }
    }
    __syncthreads();

    f32x4 a2[2];
#pragma unroll
    for (int p = 0; p < 2; ++p) a2[p] = (f32x4){0.f, 0.f, 0.f, 0.f};
#pragma unroll
    for (int kt = 0; kt < 8; ++kt) {
        short8 axx = *(const short8*)(d1b + swz(l15, kt * 64 + lg * 16, 512));
#pragma unroll
        for (int p = 0; p < 2; ++p) a2[p] = mfma16(axx, w2f[p][kt], a2[p]);
    }
#pragma unroll
    for (int p = 0; p < 2; ++p) {
        float bb = b2[wv * 32 + p * 16 + l15];
#pragma unroll
        for (int j = 0; j < 4; ++j)
            d2b[(lg * 4 + j) * 132 + wv * 32 + p * 16 + l15] = lky(a2[p][j] + bb);
    }
    __syncthreads();

    if (tid < 16) {
        float s = fb[0];
#pragma unroll 8
        for (int k = 0; k < 128; ++k) s += d2b[tid * 132 + k] * wfl[k];
        out[r0 + tid] = sigf(s);
    }
}

extern "C" void kernel_launch(void* const* d_in, const int* in_sizes, int n_in,
                              void* d_out, int out_size, void* d_ws, size_t ws_size,
                              hipStream_t stream)
{
    const float* inputs   = (const float*)d_in[0];
    const float* gru_W    = (const float*)d_in[1];
    const float* gru_U    = (const float*)d_in[2];
    const float* gru_b    = (const float*)d_in[3];
    const float* att_W1   = (const float*)d_in[4];
    const float* att_b1   = (const float*)d_in[5];
    const float* att_W2   = (const float*)d_in[6];
    const float* att_b2   = (const float*)d_in[7];
    const float* att_W3   = (const float*)d_in[8];
    const float* att_b3   = (const float*)d_in[9];
    const float* au_Wu    = (const float*)d_in[10];
    const float* au_bu    = (const float*)d_in[11];
    const float* au_Uu    = (const float*)d_in[12];
    const float* au_Wr    = (const float*)d_in[13];
    const float* au_br    = (const float*)d_in[14];
    const float* au_Ur    = (const float*)d_in[15];
    const float* au_Wc    = (const float*)d_in[16];
    const float* au_bc    = (const float*)d_in[17];
    const float* au_Uc    = (const float*)d_in[18];
    const float* bn_gamma = (const float*)d_in[19];
    const float* bn_beta  = (const float*)d_in[20];
    const float* bn_mean  = (const float*)d_in[21];
    const float* bn_var   = (const float*)d_in[22];
    const float* d_W1     = (const float*)d_in[23];
    const float* d_b1     = (const float*)d_in[24];
    const float* d_W2     = (const float*)d_in[25];
    const float* d_b2     = (const float*)d_in[26];
    const float* f_W      = (const float*)d_in[27];
    const float* f_b      = (const float*)d_in[28];

    char* w = (char*)d_ws;
    uint2* hs4          = (uint2*)w;
    float* ats          = (float*)(w + 52428800);
    float* hf           = (float*)(w + 53248000);
    float* nterm        = (float*)(w + 55345152);
    unsigned short* Wg  = (unsigned short*)(w + 57442304);
    unsigned short* Ug  = (unsigned short*)(w + 57540608);
    unsigned short* Wau = (unsigned short*)(w + 57638912);
    unsigned short* Uau = (unsigned short*)(w + 57737216);
    unsigned short* WA  = (unsigned short*)(w + 57835520);
    unsigned short* WN  = (unsigned short*)(w + 57901056);
    unsigned short* AW2 = (unsigned short*)(w + 57933824);
    unsigned short* DW1 = (unsigned short*)(w + 57950208);
    unsigned short* DW2 = (unsigned short*)(w + 58081280);
    float* bp           = (float*)(w + 58146816);

    pack_all<<<994, 256, 0, stream>>>(
        gru_W, gru_U, au_Wu, au_Wr, au_Wc, au_Uu, au_Ur, au_Uc,
        att_W1, att_W2, d_W1, d_W2, au_bu, au_br, au_bc,
        Wg, Ug, Wau, Uau, WA, WN, AW2, DW1, DW2, bp);
    nterm_kernel<<<64, 512, 0, stream>>>(inputs, WN, att_b1, nterm);
    gru_attn<<<256, 512, 0, stream>>>(inputs, Wg, Ug, gru_b, WA, AW2, att_b2,
                                      nterm, att_W3, att_b3, hs4, ats);
    augru_mfma<<<256, 512, 0, stream>>>(hs4, Wau, Uau, bp, ats, hf);
    final_mfma<<<256, 256, 0, stream>>>(hf, inputs, bn_gamma, bn_beta, bn_mean, bn_var,
                                        DW1, d_b1, DW2, d_b2, f_W, f_b, (float*)d_out);
}

// Round 16
// 165.431 us; speedup vs baseline: 2.2133x; 1.0089x over previous
//
#include <hip/hip_runtime.h>
#include <hip/hip_bf16.h>
#include <math.h>

// DIEN bf16-MFMA v14: r11/r15 structure, but gru_attn's L1/L2 weights (WA, AW2)
// moved to LDS (r12's verified staging code). Hypothesis: nominal 144 weight
// VGPRs > the allocator's hard 128 cap -> compiler remats waf/w2f loads per
// step from L2 (invisible in FETCH_SIZE which counts HBM only). Holding only
// wf/uf (96) in registers removes the remat candidate set entirely.
// ws layout (bytes): unchanged.

#define LK 0.0003f

typedef __attribute__((ext_vector_type(8))) short short8;
typedef __attribute__((ext_vector_type(4))) float f32x4;

__device__ __forceinline__ float sigf(float x) {
    return __builtin_amdgcn_rcpf(1.0f + __expf(-x));
}
__device__ __forceinline__ float tanhfast(float x) {
    return fmaf(2.0f, __builtin_amdgcn_rcpf(1.0f + __expf(-2.0f * x)), -1.0f);
}
__device__ __forceinline__ float lky(float v) { return v >= 0.0f ? v : LK * v; }
__device__ __forceinline__ unsigned short f2bf(float f) {
    __bf16 b = (__bf16)f;
    return *reinterpret_cast<unsigned short*>(&b);
}
__device__ __forceinline__ unsigned pk2(float a, float b) {
    return (unsigned)f2bf(a) | ((unsigned)f2bf(b) << 16);
}
__device__ __forceinline__ int swz(int row, int kbyte, int stride) {
    return row * stride + (kbyte ^ ((row & 7) << 4));
}
__device__ __forceinline__ f32x4 mfma16(short8 a, short8 b, f32x4 c) {
    return __builtin_amdgcn_mfma_f32_16x16x32_bf16(a, b, c, 0, 0, 0);
}
// Barrier that waits only on LDS ops (global stores here have no intra-kernel
// reader; loads are drained at their uses by compiler-inserted vmcnt).
__device__ __forceinline__ void barrier_lds() {
    __builtin_amdgcn_sched_barrier(0);
    asm volatile("s_waitcnt lgkmcnt(0)" ::: "memory");
    __builtin_amdgcn_sched_barrier(0);
    __builtin_amdgcn_s_barrier();
    __builtin_amdgcn_sched_barrier(0);
}

// ---------------- pack & transpose all weights to bf16 [n][k] panels ----------------
__global__ void pack_all(
    const float* __restrict__ gW, const float* __restrict__ gU,
    const float* __restrict__ aWu, const float* __restrict__ aWr, const float* __restrict__ aWc,
    const float* __restrict__ aUu, const float* __restrict__ aUr, const float* __restrict__ aUc,
    const float* __restrict__ tW1, const float* __restrict__ tW2,
    const float* __restrict__ dW1, const float* __restrict__ dW2,
    const float* __restrict__ abu, const float* __restrict__ abr, const float* __restrict__ abc,
    unsigned short* __restrict__ Wg, unsigned short* __restrict__ Ug,
    unsigned short* __restrict__ Wau, unsigned short* __restrict__ Uau,
    unsigned short* __restrict__ WA, unsigned short* __restrict__ WN,
    unsigned short* __restrict__ AW2,
    unsigned short* __restrict__ DW1, unsigned short* __restrict__ DW2,
    float* __restrict__ bp)
{
    int i = blockIdx.x * 256 + threadIdx.x;
    if (i < 49152) {
        int n = i >> 7, k = i & 127;
        Wg[i] = f2bf(gW[k * 384 + n]);
        Ug[i] = f2bf(gU[k * 384 + n]);
    } else if (i < 98304) {
        int j = i - 49152; int n = j >> 7, k = j & 127;
        int g = n >> 7, c = n & 127;
        const float* s = (g == 0) ? aWu : (g == 1) ? aWr : aWc;
        const float* u = (g == 0) ? aUu : (g == 1) ? aUr : aUc;
        Wau[j] = f2bf(s[k * 128 + c]);
        Uau[j] = f2bf(u[k * 128 + c]);
    } else if (i < 131072) {
        int j = i - 98304; int n = j >> 8, k = j & 255;
        float v = (k < 128) ? (tW1[k * 128 + n] - tW1[(128 + k) * 128 + n])
                            : tW1[(384 + (k - 128)) * 128 + n];
        WA[j] = f2bf(v);
    } else if (i < 147456) {
        int j = i - 131072; int n = j >> 7, k = j & 127;
        WN[j] = f2bf(tW1[(128 + k) * 128 + n] + tW1[(256 + k) * 128 + n]);
    } else if (i < 155648) {
        int j = i - 147456; int n = j >> 7, k = j & 127;
        AW2[j] = f2bf(tW2[k * 64 + n]);
    } else if (i < 221184) {
        int j = i - 155648; int n = j >> 8, k = j & 255;
        DW1[j] = f2bf(dW1[k * 256 + n]);
    } else if (i < 253952) {
        int j = i - 221184; int n = j >> 8, k = j & 255;
        DW2[j] = f2bf(dW2[k * 128 + n]);
    } else if (i < 254336) {
        int j = i - 253952;
        bp[j] = (j < 128) ? abu[j] : (j < 256) ? abr[j - 128] : abc[j - 256];
    }
}

// ---------------- nterm = news @ WN + b1 ----------------
__global__ __launch_bounds__(512, 2) void nterm_kernel(
    const float* __restrict__ inputs, const unsigned short* __restrict__ WN,
    const float* __restrict__ b1, float* __restrict__ nterm)
{
    __shared__ __align__(16) unsigned char nb[64 * 256];

    const int tid = threadIdx.x;
    const int wv = tid >> 6, l = tid & 63, l15 = l & 15, lg = l >> 4;
    const size_t b0 = (size_t)blockIdx.x * 64;

    {
        int r = tid >> 3, c = tid & 7;
        const float* src = inputs + ((b0 + r) * 51 + 50) * 128 + c * 16;
        float4 v0 = *(const float4*)(src);
        float4 v1 = *(const float4*)(src + 4);
        float4 v2 = *(const float4*)(src + 8);
        float4 v3 = *(const float4*)(src + 12);
        *(uint4*)(nb + swz(r, c * 32, 256)) =
            make_uint4(pk2(v0.x, v0.y), pk2(v0.z, v0.w), pk2(v1.x, v1.y), pk2(v1.z, v1.w));
        *(uint4*)(nb + swz(r, c * 32 + 16, 256)) =
            make_uint4(pk2(v2.x, v2.y), pk2(v2.z, v2.w), pk2(v3.x, v3.y), pk2(v3.z, v3.w));
    }
    __syncthreads();

    short8 wf[4];
#pragma unroll
    for (int kt = 0; kt < 4; ++kt)
        wf[kt] = *(const short8*)(WN + (wv * 16 + l15) * 128 + kt * 32 + lg * 8);

    f32x4 acc[4];
#pragma unroll
    for (int rt = 0; rt < 4; ++rt) acc[rt] = (f32x4){0.f, 0.f, 0.f, 0.f};
#pragma unroll
    for (int rt = 0; rt < 4; ++rt)
#pragma unroll
        for (int kt = 0; kt < 4; ++kt) {
            short8 axx = *(const short8*)(nb + swz(rt * 16 + l15, kt * 64 + lg * 16, 256));
            acc[rt] = mfma16(axx, wf[kt], acc[rt]);
        }
    float bb = b1[wv * 16 + l15];
#pragma unroll
    for (int rt = 0; rt < 4; ++rt)
#pragma unroll
        for (int j = 0; j < 4; ++j)
            nterm[(b0 + rt * 16 + lg * 4 + j) * 128 + wv * 16 + l15] = acc[rt][j] + bb;
}

// ---------------- GRU + attention fused persistent recurrence ----------------
// L1/L2 weights in LDS (swizzled); only wf/uf (96 VGPR) register-resident.
__global__ __launch_bounds__(512, 2) void gru_attn(
    const float* __restrict__ inputs, const unsigned short* __restrict__ Wt,
    const unsigned short* __restrict__ Ut, const float* __restrict__ gb,
    const unsigned short* __restrict__ WA, const unsigned short* __restrict__ AW2,
    const float* __restrict__ ab2, const float* __restrict__ nterm,
    const float* __restrict__ W3, const float* __restrict__ b3,
    uint2* __restrict__ hs4, float* __restrict__ ats)
{
    __shared__ __align__(16) unsigned char WAl[128 * 512];   // 64KB L1 weights swz
    __shared__ __align__(16) unsigned char AW2l[64 * 256];   // 16KB L2 weights swz
    __shared__ __align__(16) unsigned char xbuf[2][4096];
    __shared__ __align__(16) unsigned char hbuf[2][4096];
    __shared__ __align__(16) unsigned char pbuf[2][4096];
    __shared__ __align__(16) unsigned char a1buf[2][4096];
    __shared__ float a2buf[2][16 * 65];
    __shared__ float w3l[64];

    const int tid = threadIdx.x;
    const int wv = tid >> 6, l = tid & 63, l15 = l & 15, lg = l >> 4;
    const size_t row0 = (size_t)blockIdx.x * 16;
    const int ucol = wv * 16 + l15;

    short8 wf[3][4], uf[3][4];
#pragma unroll
    for (int g = 0; g < 3; ++g)
#pragma unroll
        for (int kt = 0; kt < 4; ++kt) {
            int n = g * 128 + ucol;
            int k0 = kt * 32 + lg * 8;
            wf[g][kt] = *(const short8*)(Wt + n * 128 + k0);
            uf[g][kt] = *(const short8*)(Ut + n * 128 + k0);
        }
    // L1/L2 weights -> LDS (swizzled)  [verified code path from r12]
    for (int i = tid; i < 4096; i += 512) {               // WA: 128 x 256 bf16
        int n = i >> 5, kk = (i & 31) * 8;
        *(short8*)(WAl + n * 512 + ((kk * 2) ^ ((n & 7) << 4))) =
            *(const short8*)(WA + n * 256 + kk);
    }
    for (int i = tid; i < 1024; i += 512) {               // AW2: 64 x 128 bf16
        int n = i >> 4, kk = (i & 15) * 8;
        *(short8*)(AW2l + n * 256 + ((kk * 2) ^ ((n & 7) << 4))) =
            *(const short8*)(AW2 + n * 128 + kk);
    }
    const int n2 = (wv & 3) * 16 + l15;
    const float b2v = (wv < 4) ? ab2[n2] : 0.f;
    const float b3v = b3[0];
    if (tid < 64) w3l[tid] = W3[tid];

    const float bx2 = gb[256 + ucol], bh2 = gb[640 + ucol];
    const float bz  = gb[ucol] + gb[384 + ucol];
    const float br  = gb[128 + ucol] + gb[512 + ucol];

    float nt4[4], news4[4];
#pragma unroll
    for (int j = 0; j < 4; ++j) {
        int m = lg * 4 + j;
        nt4[j]   = nterm[(row0 + m) * 128 + ucol];
        news4[j] = inputs[((row0 + m) * 51 + 50) * 128 + ucol];
    }
    uint2* hs4p = hs4 + ((row0 >> 2) + lg) * 6400 + ucol;

    const int sr = tid >> 5, ss = tid & 31;
    const float* xsrc = inputs + (row0 + sr) * 51 * 128 + ss * 4;

    int rdo[4], wro[4], wafo[8], w2o[4];
#pragma unroll
    for (int kt = 0; kt < 4; ++kt) rdo[kt] = swz(l15, kt * 64 + lg * 16, 256);
#pragma unroll
    for (int j = 0; j < 4; ++j)   wro[j] = swz(lg * 4 + j, ucol * 2, 256);
#pragma unroll
    for (int kt = 0; kt < 8; ++kt)
        wafo[kt] = ucol * 512 + ((kt * 64 + lg * 16) ^ ((ucol & 7) << 4));
#pragma unroll
    for (int kt = 0; kt < 4; ++kt)
        w2o[kt] = n2 * 256 + ((kt * 64 + lg * 16) ^ ((n2 & 7) << 4));
    const int xwo = swz(sr, ss * 8, 256);

    *(uint2*)(hbuf[0] + tid * 8) = make_uint2(0u, 0u);
    {
        float4 v = *(const float4*)(xsrc);
        *(uint2*)(xbuf[0] + xwo) = make_uint2(pk2(v.x, v.y), pk2(v.z, v.w));
    }
    float hreg[4] = {0.f, 0.f, 0.f, 0.f};
    __syncthreads();

#define STEP(T, PF, DOGRU, DOL1, DOL2, DODOT) do {                                  \
    const int p_ = (T) & 1;                                                          \
    float4 xpf_;                                                                     \
    if (PF) xpf_ = *(const float4*)(xsrc + (size_t)((T) + 1) * 128);                 \
    short8 ah_[4];                                                                   \
    if (DOGRU || DOL1) {                                                             \
        _Pragma("unroll")                                                            \
        for (int kt = 0; kt < 4; ++kt)                                               \
            ah_[kt] = *(const short8*)(hbuf[p_] + rdo[kt]);                          \
    }                                                                                \
    short8 ax_[4], pa_[4];                                                           \
    if (DOGRU) {                                                                     \
        _Pragma("unroll")                                                            \
        for (int kt = 0; kt < 4; ++kt)                                               \
            ax_[kt] = *(const short8*)(xbuf[p_] + rdo[kt]);                          \
    }                                                                                \
    if (DOL1) {                                                                      \
        _Pragma("unroll")                                                            \
        for (int kt = 0; kt < 4; ++kt)                                               \
            pa_[kt] = *(const short8*)(pbuf[p_] + rdo[kt]);                          \
    }                                                                                \
    f32x4 accx_[3], acch_[3], lacc_;                                                 \
    __builtin_amdgcn_s_setprio(1);                                                   \
    if (DOGRU) {                                                                     \
        _Pragma("unroll")                                                            \
        for (int g = 0; g < 3; ++g) {                                                \
            accx_[g] = (f32x4){0.f, 0.f, 0.f, 0.f};                                  \
            acch_[g] = (f32x4){0.f, 0.f, 0.f, 0.f};                                  \
        }                                                                            \
        _Pragma("unroll")                                                            \
        for (int kt = 0; kt < 4; ++kt)                                               \
            _Pragma("unroll")                                                        \
            for (int g = 0; g < 3; ++g) {                                            \
                accx_[g] = mfma16(ax_[kt], wf[g][kt], accx_[g]);                     \
                acch_[g] = mfma16(ah_[kt], uf[g][kt], acch_[g]);                     \
            }                                                                        \
    }                                                                                \
    if (DOL1) {                                                                      \
        lacc_ = (f32x4){0.f, 0.f, 0.f, 0.f};                                         \
        _Pragma("unroll")                                                            \
        for (int kt = 0; kt < 4; ++kt) {                                             \
            short8 wa_ = *(const short8*)(WAl + wafo[kt]);                           \
            lacc_ = mfma16(ah_[kt], wa_, lacc_);                                     \
        }                                                                            \
        _Pragma("unroll")                                                            \
        for (int kt = 0; kt < 4; ++kt) {                                             \
            short8 wa_ = *(const short8*)(WAl + wafo[4 + kt]);                       \
            lacc_ = mfma16(pa_[kt], wa_, lacc_);                                     \
        }                                                                            \
    }                                                                                \
    __builtin_amdgcn_s_setprio(0);                                                   \
    if (DOGRU) {                                                                     \
        unsigned short hbv_[4];                                                      \
        _Pragma("unroll")                                                            \
        for (int j = 0; j < 4; ++j) {                                                \
            float z  = sigf(accx_[0][j] + acch_[0][j] + bz);                         \
            float r  = sigf(accx_[1][j] + acch_[1][j] + br);                         \
            float hc = tanhfast(accx_[2][j] + bx2 + r * (acch_[2][j] + bh2));        \
            float hn = fmaf(z, hreg[j] - hc, hc);                                    \
            hreg[j] = hn;                                                            \
            hbv_[j] = f2bf(hn);                                                      \
            *(unsigned short*)(hbuf[p_ ^ 1] + wro[j]) = hbv_[j];                     \
            *(unsigned short*)(pbuf[p_ ^ 1] + wro[j]) = f2bf(hn * news4[j]);         \
        }                                                                            \
        hs4p[(size_t)(T) * 128] =                                                    \
            make_uint2((unsigned)hbv_[0] | ((unsigned)hbv_[1] << 16),                \
                       (unsigned)hbv_[2] | ((unsigned)hbv_[3] << 16));               \
    }                                                                                \
    if (DOL1) {                                                                      \
        _Pragma("unroll")                                                            \
        for (int j = 0; j < 4; ++j) {                                                \
            float v = fmaxf(lacc_[j] + nt4[j], 0.f);                                 \
            *(unsigned short*)(a1buf[p_] + wro[j]) = f2bf(v);                        \
        }                                                                            \
    }                                                                                \
    if (DOL2) {                                                                      \
        if (wv < 4) {                                                                \
            f32x4 c2_ = (f32x4){0.f, 0.f, 0.f, 0.f};                                 \
            _Pragma("unroll")                                                        \
            for (int kt = 0; kt < 4; ++kt) {                                         \
                short8 aa_ = *(const short8*)(a1buf[p_ ^ 1] + rdo[kt]);              \
                short8 w2_ = *(const short8*)(AW2l + w2o[kt]);                       \
                c2_ = mfma16(aa_, w2_, c2_);                                         \
            }                                                                        \
            _Pragma("unroll")                                                        \
            for (int j = 0; j < 4; ++j)                                              \
                a2buf[p_][(lg * 4 + j) * 65 + n2] = fmaxf(c2_[j] + b2v, 0.f);        \
        }                                                                            \
    }                                                                                \
    if (DODOT) {                                                                     \
        if (tid >= 256) {  /* waves 4-7: 16 rows x 16 lanes */                       \
            int rrow_ = (tid - 256) >> 4, cc_ = tid & 15;                            \
            const float* a2r_ = &a2buf[p_ ^ 1][rrow_ * 65];                          \
            float s_ = a2r_[cc_] * w3l[cc_] + a2r_[cc_ + 16] * w3l[cc_ + 16]         \
                     + a2r_[cc_ + 32] * w3l[cc_ + 32] + a2r_[cc_ + 48] * w3l[cc_ + 48];\
            s_ += __shfl_xor(s_, 8, 16);                                             \
            s_ += __shfl_xor(s_, 4, 16);                                             \
            s_ += __shfl_xor(s_, 2, 16);                                             \
            s_ += __shfl_xor(s_, 1, 16);                                             \
            if ((tid & 15) == 0)                                                     \
                ats[(row0 + rrow_) * 50 + ((T) - 3)] = sigf(s_ + b3v);               \
        }                                                                            \
    }                                                                                \
    if (PF)                                                                          \
        *(uint2*)(xbuf[p_ ^ 1] + xwo) =                                              \
            make_uint2(pk2(xpf_.x, xpf_.y), pk2(xpf_.z, xpf_.w));                    \
    barrier_lds();                                                                   \
} while (0)

    STEP(0, 1, 1, 0, 0, 0);
    STEP(1, 1, 1, 1, 0, 0);
    STEP(2, 1, 1, 1, 1, 0);
    for (int t = 3; t <= 48; ++t) STEP(t, 1, 1, 1, 1, 1);
    STEP(49, 0, 1, 1, 1, 1);
    STEP(50, 0, 0, 1, 1, 1);
    STEP(51, 0, 0, 0, 1, 1);
    STEP(52, 0, 0, 0, 0, 1);
#undef STEP
}

// ---------------- AUGRU: MFMA recurrence, lgkmcnt-only barrier ----------------
__global__ __launch_bounds__(512, 2) void augru_mfma(
    const uint2* __restrict__ hs4, const unsigned short* __restrict__ Wt,
    const unsigned short* __restrict__ Ut, const float* __restrict__ bp,
    const float* __restrict__ ats, float* __restrict__ hf)
{
    __shared__ __align__(16) unsigned char xbuf[2][4096];
    __shared__ __align__(16) unsigned char hbuf[2][4096];
    __shared__ float atsl[16 * 50];

    const int tid = threadIdx.x;
    const int wv = tid >> 6, l = tid & 63, l15 = l & 15, lg = l >> 4;
    const size_t row0 = (size_t)blockIdx.x * 16;
    const int ucol = wv * 16 + l15;

    short8 wf[3][4], uf[3][4];
#pragma unroll
    for (int g = 0; g < 3; ++g)
#pragma unroll
        for (int kt = 0; kt < 4; ++kt) {
            int n = g * 128 + ucol;
            int k0 = kt * 32 + lg * 8;
            wf[g][kt] = *(const short8*)(Wt + n * 128 + k0);
            uf[g][kt] = *(const short8*)(Ut + n * 128 + k0);
        }
    const float bx0 = bp[ucol], bx1 = bp[128 + ucol], bx2 = bp[256 + ucol];

    const int sg = tid >> 7, sc = tid & 127;
    const uint2* xsrc2 = hs4 + ((row0 >> 2) + sg) * 6400 + sc;

    int rdo[4], wro[4];
#pragma unroll
    for (int kt = 0; kt < 4; ++kt) rdo[kt] = swz(l15, kt * 64 + lg * 16, 256);
#pragma unroll
    for (int j = 0; j < 4; ++j)   wro[j] = swz(lg * 4 + j, ucol * 2, 256);
    int xwo4[4];
#pragma unroll
    for (int q = 0; q < 4; ++q)   xwo4[q] = swz(4 * sg + q, sc * 2, 256);

    *(uint2*)(hbuf[0] + tid * 8) = make_uint2(0u, 0u);
    if (tid < 400) {
        atsl[tid] = ats[row0 * 50 + tid];
        atsl[tid + 400] = ats[row0 * 50 + tid + 400];
    }
    {
        uint2 u = xsrc2[0];
        *(unsigned short*)(xbuf[0] + xwo4[0]) = (unsigned short)(u.x & 0xffff);
        *(unsigned short*)(xbuf[0] + xwo4[1]) = (unsigned short)(u.x >> 16);
        *(unsigned short*)(xbuf[0] + xwo4[2]) = (unsigned short)(u.y & 0xffff);
        *(unsigned short*)(xbuf[0] + xwo4[3]) = (unsigned short)(u.y >> 16);
    }
    float hreg[4] = {0.f, 0.f, 0.f, 0.f};
    __syncthreads();

    for (int t = 0; t < 50; ++t) {
        const int p = t & 1;
        uint2 xnext;
        if (t < 49) xnext = xsrc2[(size_t)(t + 1) * 128];

        short8 ax[4], ah[4];
#pragma unroll
        for (int kt = 0; kt < 4; ++kt) {
            ax[kt] = *(const short8*)(xbuf[p] + rdo[kt]);
            ah[kt] = *(const short8*)(hbuf[p] + rdo[kt]);
        }
        f32x4 accx[3], acch[3];
#pragma unroll
        for (int g = 0; g < 3; ++g) {
            accx[g] = (f32x4){0.f, 0.f, 0.f, 0.f};
            acch[g] = (f32x4){0.f, 0.f, 0.f, 0.f};
        }
        __builtin_amdgcn_s_setprio(1);
#pragma unroll
        for (int kt = 0; kt < 4; ++kt)
#pragma unroll
            for (int g = 0; g < 3; ++g) {
                accx[g] = mfma16(ax[kt], wf[g][kt], accx[g]);
                acch[g] = mfma16(ah[kt], uf[g][kt], acch[g]);
            }
        __builtin_amdgcn_s_setprio(0);
#pragma unroll
        for (int j = 0; j < 4; ++j) {
            int m = lg * 4 + j;
            float u  = sigf(accx[0][j] + bx0 + acch[0][j]);
            float r  = sigf(accx[1][j] + bx1 + acch[1][j]);
            float c  = tanhfast(accx[2][j] + bx2 + r * acch[2][j]);
            float uu = atsl[m * 50 + t] * u;
            float hn = fmaf(uu, c - hreg[j], hreg[j]);
            hreg[j] = hn;
            *(unsigned short*)(hbuf[p ^ 1] + wro[j]) = f2bf(hn);
        }
        if (t < 49) {
            *(unsigned short*)(xbuf[p ^ 1] + xwo4[0]) = (unsigned short)(xnext.x & 0xffff);
            *(unsigned short*)(xbuf[p ^ 1] + xwo4[1]) = (unsigned short)(xnext.x >> 16);
            *(unsigned short*)(xbuf[p ^ 1] + xwo4[2]) = (unsigned short)(xnext.y & 0xffff);
            *(unsigned short*)(xbuf[p ^ 1] + xwo4[3]) = (unsigned short)(xnext.y >> 16);
        }
        barrier_lds();
    }
#pragma unroll
    for (int j = 0; j < 4; ++j)
        hf[(row0 + lg * 4 + j) * 128 + ucol] = hreg[j];
}

// ---------------- final: BN + 256->256->128->1, MFMA ----------------
__global__ __launch_bounds__(256, 2) void final_mfma(
    const float* __restrict__ hfv, const float* __restrict__ inputs,
    const float* __restrict__ gam, const float* __restrict__ bet,
    const float* __restrict__ mu, const float* __restrict__ var,
    const unsigned short* __restrict__ W1t, const float* __restrict__ b1,
    const unsigned short* __restrict__ W2t, const float* __restrict__ b2,
    const float* __restrict__ fW, const float* __restrict__ fb,
    float* __restrict__ out)
{
    __shared__ __align__(16) unsigned char xnb[16 * 512];
    __shared__ __align__(16) unsigned char d1b[16 * 512];
    __shared__ float d2b[16 * 132];
    __shared__ float wfl[128];

    const int tid = threadIdx.x;
    const int wv = tid >> 6, l = tid & 63, l15 = l & 15, lg = l >> 4;
    const size_t r0 = (size_t)blockIdx.x * 16;

    short8 w1f[4][8];
#pragma unroll
    for (int p = 0; p < 4; ++p)
#pragma unroll
        for (int kt = 0; kt < 8; ++kt) {
            int n = wv * 64 + p * 16 + l15;
            w1f[p][kt] = *(const short8*)(W1t + n * 256 + kt * 32 + lg * 8);
        }
    short8 w2f[2][8];
#pragma unroll
    for (int p = 0; p < 2; ++p)
#pragma unroll
        for (int kt = 0; kt < 8; ++kt) {
            int n = wv * 32 + p * 16 + l15;
            w2f[p][kt] = *(const short8*)(W2t + n * 256 + kt * 32 + lg * 8);
        }
    if (tid < 128) wfl[tid] = fW[tid];

    {
        int r = tid >> 4, c = tid & 15, k0 = c * 16;
        float v[16];
#pragma unroll
        for (int q = 0; q < 16; ++q) {
            int k = k0 + q;
            float x = (k < 128) ? hfv[(r0 + r) * 128 + k]
                                : inputs[((r0 + r) * 51 + 50) * 128 + (k - 128)];
            float s = gam[k] * rsqrtf(var[k] + 0.001f);
            v[q] = (x - mu[k]) * s + bet[k];
        }
        *(uint4*)(xnb + swz(r, k0 * 2, 512)) =
            make_uint4(pk2(v[0], v[1]), pk2(v[2], v[3]), pk2(v[4], v[5]), pk2(v[6], v[7]));
        *(uint4*)(xnb + swz(r, k0 * 2 + 16, 512)) =
            make_uint4(pk2(v[8], v[9]), pk2(v[10], v[11]), pk2(v[12], v[13]), pk2(v[14], v[15]));
    }
    __syncthreads();

    f32x4 a1[4];
#pragma unroll
    for (int p = 0; p < 4; ++p) a1[p] = (f32x4){0.f, 0.f, 0.f, 0.f};
#pragma unroll
    for (int kt = 0; kt < 8; ++kt) {
        short8 axx = *(const short8*)(xnb + swz(l15, kt * 64 + lg * 16, 512));
#pragma unroll
        for (int p = 0; p < 4; ++p) a1[p] = mfma16(axx, w1f[p][kt], a1[p]);
    }
#pragma unroll
    for (int p = 0; p < 4; ++p) {
        float bb = b1[wv * 64 + p * 16 + l15];
#pragma unroll
        for (int j = 0; j < 4; ++j) {
            int row = lg * 4 + j, col = wv * 64 + p * 16 + l15;
            *(unsigned short*)(d1b + swz(row, col * 2, 512)) = f2bf(lky(a1[p][j] + bb));
        }
    }
    __syncthreads();

    f32x4 a2[2];
#pragma unroll
    for (int p = 0; p < 2; ++p) a2[p] = (f32x4){0.f, 0.f, 0.f, 0.f};
#pragma unroll
    for (int kt = 0; kt < 8; ++kt) {
        short8 axx = *(const short8*)(d1b + swz(l15, kt * 64 + lg * 16, 512));
#pragma unroll
        for (int p = 0; p < 2; ++p) a2[p] = mfma16(axx, w2f[p][kt], a2[p]);
    }
#pragma unroll
    for (int p = 0; p < 2; ++p) {
        float bb = b2[wv * 32 + p * 16 + l15];
#pragma unroll
        for (int j = 0; j < 4; ++j)
            d2b[(lg * 4 + j) * 132 + wv * 32 + p * 16 + l15] = lky(a2[p][j] + bb);
    }
    __syncthreads();

    if (tid < 16) {
        float s = fb[0];
#pragma unroll 8
        for (int k = 0; k < 128; ++k) s += d2b[tid * 132 + k] * wfl[k];
        out[r0 + tid] = sigf(s);
    }
}

extern "C" void kernel_launch(void* const* d_in, const int* in_sizes, int n_in,
                              void* d_out, int out_size, void* d_ws, size_t ws_size,
                              hipStream_t stream)
{
    const float* inputs   = (const float*)d_in[0];
    const float* gru_W    = (const float*)d_in[1];
    const float* gru_U    = (const float*)d_in[2];
    const float* gru_b    = (const float*)d_in[3];
    const float* att_W1   = (const float*)d_in[4];
    const float* att_b1   = (const float*)d_in[5];
    const float* att_W2   = (const float*)d_in[6];
    const float* att_b2   = (const float*)d_in[7];
    const float* att_W3   = (const float*)d_in[8];
    const float* att_b3   = (const float*)d_in[9];
    const float* au_Wu    = (const float*)d_in[10];
    const float* au_bu    = (const float*)d_in[11];
    const float* au_Uu    = (const float*)d_in[12];
    const float* au_Wr    = (const float*)d_in[13];
    const float* au_br    = (const float*)d_in[14];
    const float* au_Ur    = (const float*)d_in[15];
    const float* au_Wc    = (const float*)d_in[16];
    const float* au_bc    = (const float*)d_in[17];
    const float* au_Uc    = (const float*)d_in[18];
    const float* bn_gamma = (const float*)d_in[19];
    const float* bn_beta  = (const float*)d_in[20];
    const float* bn_mean  = (const float*)d_in[21];
    const float* bn_var   = (const float*)d_in[22];
    const float* d_W1     = (const float*)d_in[23];
    const float* d_b1     = (const float*)d_in[24];
    const float* d_W2     = (const float*)d_in[25];
    const float* d_b2     = (const float*)d_in[26];
    const float* f_W      = (const float*)d_in[27];
    const float* f_b      = (const float*)d_in[28];

    char* w = (char*)d_ws;
    uint2* hs4          = (uint2*)w;
    float* ats          = (float*)(w + 52428800);
    float* hf           = (float*)(w + 53248000);
    float* nterm        = (float*)(w + 55345152);
    unsigned short* Wg  = (unsigned short*)(w + 57442304);
    unsigned short* Ug  = (unsigned short*)(w + 57540608);
    unsigned short* Wau = (unsigned short*)(w + 57638912);
    unsigned short* Uau = (unsigned short*)(w + 57737216);
    unsigned short* WA  = (unsigned short*)(w + 57835520);
    unsigned short* WN  = (unsigned short*)(w + 57901056);
    unsigned short* AW2 = (unsigned short*)(w + 57933824);
    unsigned short* DW1 = (unsigned short*)(w + 57950208);
    unsigned short* DW2 = (unsigned short*)(w + 58081280);
    float* bp           = (float*)(w + 58146816);

    pack_all<<<994, 256, 0, stream>>>(
        gru_W, gru_U, au_Wu, au_Wr, au_Wc, au_Uu, au_Ur, au_Uc,
        att_W1, att_W2, d_W1, d_W2, au_bu, au_br, au_bc,
        Wg, Ug, Wau, Uau, WA, WN, AW2, DW1, DW2, bp);
    nterm_kernel<<<64, 512, 0, stream>>>(inputs, WN, att_b1, nterm);
    gru_attn<<<256, 512, 0, stream>>>(inputs, Wg, Ug, gru_b, WA, AW2, att_b2,
                                      nterm, att_W3, att_b3, hs4, ats);
    augru_mfma<<<256, 512, 0, stream>>>(hs4, Wau, Uau, bp, ats, hf);
    final_mfma<<<256, 256, 0, stream>>>(hf, inputs, bn_gamma, bn_beta, bn_mean, bn_var,
                                        DW1, d_b1, DW2, d_b2, f_W, f_b, (float*)d_out);
}